// Round 1
// baseline (34.841 us; speedup 1.0000x reference)
//
#include <hip/hip_runtime.h>

// Volume rendering (NeRF-style) for B=8, N=8192, S=128.
// One 64-lane wave per ray; lane l owns samples (2l, 2l+1).
// Exclusive cumprod of (exp(-sigma*delta)+EPS) via wave-wide shuffle scan.

namespace {
constexpr int kB = 8;
constexpr int kN = 8192;
constexpr int kS = 128;
constexpr int kRays = kB * kN;          // 65536
constexpr int kWavesPerBlock = 4;       // block = 256 threads

__global__ __launch_bounds__(256) void volrender_kernel(
    const float* __restrict__ dens,     // [rays, S]
    const float* __restrict__ rgbs,     // [rays, S, 3]
    const float* __restrict__ tvals,    // [rays, S]
    float* __restrict__ out_rgb,        // [rays, 3]
    float* __restrict__ out_w,          // [rays, S]
    float* __restrict__ out_depth,      // [rays]
    float* __restrict__ out_acc)        // [rays]
{
    const int lane = threadIdx.x & 63;
    const int wave = threadIdx.x >> 6;
    const int ray  = blockIdx.x * kWavesPerBlock + wave;

    const long base = (long)ray * kS;

    // Coalesced loads: lane l -> samples 2l, 2l+1
    const float2 t2 = *(const float2*)(tvals + base + lane * 2);
    const float2 sg = *(const float2*)(dens  + base + lane * 2);
    const float* rp = rgbs + (long)ray * kS * 3 + lane * 6;
    const float2 ra = *(const float2*)(rp + 0);   // r0.r, r0.g
    const float2 rb = *(const float2*)(rp + 2);   // r0.b, r1.r
    const float2 rc = *(const float2*)(rp + 4);   // r1.g, r1.b

    // deltas: d(i) = t(i+1)-t(i); last sample -> 1e10
    const float t_next = __shfl_down(t2.x, 1);    // t(2l+2) from lane l+1
    const float d0 = t2.y - t2.x;
    const float d1 = (lane == 63) ? 1e10f : (t_next - t2.y);

    // alpha = 1 - exp(-sigma*delta); cumprod factor = exp(-sigma*delta) + EPS
    const float e0 = expf(-sg.x * d0);
    const float e1 = expf(-sg.y * d1);
    const float a0 = 1.0f - e0;
    const float a1 = 1.0f - e1;
    const float f0 = e0 + 1e-10f;
    const float f1 = e1 + 1e-10f;

    // Inclusive product scan of per-lane pair product across the 64-lane wave
    float p = f0 * f1;
    #pragma unroll
    for (int off = 1; off < 64; off <<= 1) {
        const float q = __shfl_up(p, off);
        if (lane >= off) p *= q;
    }
    // Exclusive prefix for this lane's first sample
    float excl = __shfl_up(p, 1);
    if (lane == 0) excl = 1.0f;

    const float T0 = excl;        // trans at sample 2l
    const float T1 = excl * f0;   // trans at sample 2l+1
    const float w0 = T0 * a0;
    const float w1 = T1 * a1;

    // Coalesced weights store
    *(float2*)(out_w + base + lane * 2) = make_float2(w0, w1);

    // Per-lane partial sums
    float cr  = w0 * ra.x + w1 * rb.y;
    float cg  = w0 * ra.y + w1 * rc.x;
    float cb  = w0 * rb.x + w1 * rc.y;
    float dep = w0 * t2.x + w1 * t2.y;
    float acc = w0 + w1;

    // Wave reduction to lane 0
    #pragma unroll
    for (int off = 32; off; off >>= 1) {
        cr  += __shfl_down(cr,  off);
        cg  += __shfl_down(cg,  off);
        cb  += __shfl_down(cb,  off);
        dep += __shfl_down(dep, off);
        acc += __shfl_down(acc, off);
    }

    if (lane == 0) {
        out_rgb[ray * 3 + 0] = cr;
        out_rgb[ray * 3 + 1] = cg;
        out_rgb[ray * 3 + 2] = cb;
        out_depth[ray] = dep;
        out_acc[ray]   = acc;
    }
}
}  // namespace

extern "C" void kernel_launch(void* const* d_in, const int* in_sizes, int n_in,
                              void* d_out, int out_size, void* d_ws, size_t ws_size,
                              hipStream_t stream) {
    const float* dens  = (const float*)d_in[0];  // [B,N,S,1]
    const float* rgbs  = (const float*)d_in[1];  // [B,N,S,3]
    const float* tvals = (const float*)d_in[2];  // [B,N,S]

    float* out       = (float*)d_out;
    float* out_rgb   = out;                              // B*N*3   = 196608
    float* out_w     = out_rgb + (long)kRays * 3;        // B*N*S   = 8388608
    float* out_depth = out_w + (long)kRays * kS;         // B*N     = 65536
    float* out_acc   = out_depth + kRays;                // B*N     = 65536

    const dim3 grid(kRays / kWavesPerBlock);
    const dim3 block(kWavesPerBlock * 64);
    hipLaunchKernelGGL(volrender_kernel, grid, block, 0, stream,
                       dens, rgbs, tvals, out_rgb, out_w, out_depth, out_acc);
}

// Round 2
// 33.694 us; speedup vs baseline: 1.0340x; 1.0340x over previous
//
#include <hip/hip_runtime.h>

// Volume rendering (NeRF-style) for B=8, N=8192, S=128.
// One 64-lane wave handles TWO rays (32-lane segments); lane owns 4
// consecutive samples -> float4 loads. Segmented shuffle scan for the
// exclusive cumprod of (exp(-sigma*delta)+EPS).

namespace {
constexpr int kB = 8;
constexpr int kN = 8192;
constexpr int kS = 128;
constexpr int kRays = kB * kN;          // 65536
constexpr int kWavesPerBlock = 4;       // block = 256 threads, 8 rays/block

__global__ __launch_bounds__(256) void volrender_kernel(
    const float* __restrict__ dens,     // [rays, S]
    const float* __restrict__ rgbs,     // [rays, S, 3]
    const float* __restrict__ tvals,    // [rays, S]
    float* __restrict__ out_rgb,        // [rays, 3]
    float* __restrict__ out_w,          // [rays, S]
    float* __restrict__ out_depth,      // [rays]
    float* __restrict__ out_acc)        // [rays]
{
    const int lane = threadIdx.x & 63;
    const int wave = threadIdx.x >> 6;
    const int seg  = lane & 31;                   // lane within ray segment
    const int ray  = (blockIdx.x * kWavesPerBlock + wave) * 2 + (lane >> 5);

    const long base = (long)ray * kS + seg * 4;   // first of this lane's 4 samples

    const float4 t4 = *(const float4*)(tvals + base);
    const float4 s4 = *(const float4*)(dens  + base);
    const float* rp = rgbs + (long)ray * kS * 3 + seg * 12;
    const float4 q0 = *(const float4*)(rp + 0);   // r0 g0 b0 r1
    const float4 q1 = *(const float4*)(rp + 4);   // g1 b1 r2 g2
    const float4 q2 = *(const float4*)(rp + 8);   // b2 r3 g3 b3

    // deltas; last sample of each ray -> 1e10
    const float t_next = __shfl_down(t4.x, 1);    // next lane's first t
    const float d0 = t4.y - t4.x;
    const float d1 = t4.z - t4.y;
    const float d2 = t4.w - t4.z;
    const float d3 = (seg == 31) ? 1e10f : (t_next - t4.w);

    // e = exp(-sigma*delta); alpha = 1-e; cumprod factor f = e + EPS
    const float e0 = __expf(-s4.x * d0);
    const float e1 = __expf(-s4.y * d1);
    const float e2 = __expf(-s4.z * d2);
    const float e3 = __expf(-s4.w * d3);
    const float f0 = e0 + 1e-10f, f1 = e1 + 1e-10f;
    const float f2 = e2 + 1e-10f, f3 = e3 + 1e-10f;

    // Segmented (32-lane) inclusive product scan of per-lane product
    float p = (f0 * f1) * (f2 * f3);
    #pragma unroll
    for (int off = 1; off < 32; off <<= 1) {
        const float q = __shfl_up(p, off);
        if (seg >= off) p *= q;
    }
    float excl = __shfl_up(p, 1);                 // exclusive prefix
    if (seg == 0) excl = 1.0f;

    const float T0 = excl;
    const float T1 = T0 * f0;
    const float T2 = T1 * f1;
    const float T3 = T2 * f2;
    const float w0 = T0 * (1.0f - e0);
    const float w1 = T1 * (1.0f - e1);
    const float w2 = T2 * (1.0f - e2);
    const float w3 = T3 * (1.0f - e3);

    *(float4*)(out_w + base) = make_float4(w0, w1, w2, w3);

    // Per-lane partials
    float cr  = w0 * q0.x + w1 * q0.w + w2 * q1.z + w3 * q2.y;
    float cg  = w0 * q0.y + w1 * q1.x + w2 * q1.w + w3 * q2.z;
    float cb  = w0 * q0.z + w1 * q1.y + w2 * q2.x + w3 * q2.w;
    float dep = w0 * t4.x + w1 * t4.y + w2 * t4.z + w3 * t4.w;
    float acc = w0 + w1 + w2 + w3;

    // Butterfly reduce within the 32-lane segment (xor<32 stays in-segment)
    #pragma unroll
    for (int off = 16; off; off >>= 1) {
        cr  += __shfl_xor(cr,  off);
        cg  += __shfl_xor(cg,  off);
        cb  += __shfl_xor(cb,  off);
        dep += __shfl_xor(dep, off);
        acc += __shfl_xor(acc, off);
    }

    if (seg == 0) {
        out_rgb[ray * 3 + 0] = cr;
        out_rgb[ray * 3 + 1] = cg;
        out_rgb[ray * 3 + 2] = cb;
        out_depth[ray] = dep;
        out_acc[ray]   = acc;
    }
}
}  // namespace

extern "C" void kernel_launch(void* const* d_in, const int* in_sizes, int n_in,
                              void* d_out, int out_size, void* d_ws, size_t ws_size,
                              hipStream_t stream) {
    const float* dens  = (const float*)d_in[0];  // [B,N,S,1]
    const float* rgbs  = (const float*)d_in[1];  // [B,N,S,3]
    const float* tvals = (const float*)d_in[2];  // [B,N,S]

    float* out       = (float*)d_out;
    float* out_rgb   = out;                              // B*N*3
    float* out_w     = out_rgb + (long)kRays * 3;        // B*N*S
    float* out_depth = out_w + (long)kRays * kS;         // B*N
    float* out_acc   = out_depth + kRays;                // B*N

    const dim3 grid(kRays / (kWavesPerBlock * 2));
    const dim3 block(kWavesPerBlock * 64);
    hipLaunchKernelGGL(volrender_kernel, grid, block, 0, stream,
                       dens, rgbs, tvals, out_rgb, out_w, out_depth, out_acc);
}

// Round 4
// 33.074 us; speedup vs baseline: 1.0534x; 1.0187x over previous
//
#include <hip/hip_runtime.h>

// Volume rendering (NeRF-style) for B=8, N=8192, S=128.
// One 16-lane segment per ray (4 rays/wave); lane owns 8 consecutive
// samples -> pure float4 traffic. Segmented 16-lane shuffle scan for the
// exclusive cumprod of (exp(-sigma*delta)+EPS).

namespace {
constexpr int kB = 8;
constexpr int kN = 8192;
constexpr int kS = 128;
constexpr int kRays = kB * kN;          // 65536
constexpr int kWavesPerBlock = 4;       // block = 256 threads, 16 rays/block

typedef float f32x4 __attribute__((ext_vector_type(4)));

__global__ __launch_bounds__(256) void volrender_kernel(
    const float* __restrict__ dens,     // [rays, S]
    const float* __restrict__ rgbs,     // [rays, S, 3]
    const float* __restrict__ tvals,    // [rays, S]
    float* __restrict__ out_rgb,        // [rays, 3]
    float* __restrict__ out_w,          // [rays, S]
    float* __restrict__ out_depth,      // [rays]
    float* __restrict__ out_acc)        // [rays]
{
    const int lane = threadIdx.x & 63;
    const int wave = threadIdx.x >> 6;
    const int seg  = lane & 15;                   // lane within ray segment
    const int ray  = (blockIdx.x * kWavesPerBlock + wave) * 4 + (lane >> 4);

    const int base = ray * kS + seg * 8;          // first of this lane's 8 samples

    const float4 ta = *(const float4*)(tvals + base);
    const float4 tb = *(const float4*)(tvals + base + 4);
    const float4 sa = *(const float4*)(dens  + base);
    const float4 sb = *(const float4*)(dens  + base + 4);
    const float* rp = rgbs + ray * kS * 3 + seg * 24;
    const float4 q0 = *(const float4*)(rp + 0);
    const float4 q1 = *(const float4*)(rp + 4);
    const float4 q2 = *(const float4*)(rp + 8);
    const float4 q3 = *(const float4*)(rp + 12);
    const float4 q4 = *(const float4*)(rp + 16);
    const float4 q5 = *(const float4*)(rp + 20);

    // deltas; last sample of each ray -> 1e10
    const float t_next = __shfl_down(ta.x, 1);    // next lane's first t
    const float d0 = ta.y - ta.x;
    const float d1 = ta.z - ta.y;
    const float d2 = ta.w - ta.z;
    const float d3 = tb.x - ta.w;
    const float d4 = tb.y - tb.x;
    const float d5 = tb.z - tb.y;
    const float d6 = tb.w - tb.z;
    const float d7 = (seg == 15) ? 1e10f : (t_next - tb.w);

    // e = exp(-sigma*delta); alpha = 1-e; cumprod factor f = e + EPS
    const float e0 = __expf(-sa.x * d0);
    const float e1 = __expf(-sa.y * d1);
    const float e2 = __expf(-sa.z * d2);
    const float e3 = __expf(-sa.w * d3);
    const float e4 = __expf(-sb.x * d4);
    const float e5 = __expf(-sb.y * d5);
    const float e6 = __expf(-sb.z * d6);
    const float e7 = __expf(-sb.w * d7);
    const float f0 = e0 + 1e-10f, f1 = e1 + 1e-10f;
    const float f2 = e2 + 1e-10f, f3 = e3 + 1e-10f;
    const float f4 = e4 + 1e-10f, f5 = e5 + 1e-10f;
    const float f6 = e6 + 1e-10f, f7 = e7 + 1e-10f;

    // Segmented (16-lane) inclusive product scan of per-lane product
    float p = ((f0 * f1) * (f2 * f3)) * ((f4 * f5) * (f6 * f7));
    #pragma unroll
    for (int off = 1; off < 16; off <<= 1) {
        const float q = __shfl_up(p, off);
        if (seg >= off) p *= q;
    }
    float excl = __shfl_up(p, 1);                 // exclusive prefix
    if (seg == 0) excl = 1.0f;

    const float T0 = excl;
    const float T1 = T0 * f0;
    const float T2 = T1 * f1;
    const float T3 = T2 * f2;
    const float T4 = T3 * f3;
    const float T5 = T4 * f4;
    const float T6 = T5 * f5;
    const float T7 = T6 * f6;
    const float w0 = T0 * (1.0f - e0);
    const float w1 = T1 * (1.0f - e1);
    const float w2 = T2 * (1.0f - e2);
    const float w3 = T3 * (1.0f - e3);
    const float w4 = T4 * (1.0f - e4);
    const float w5 = T5 * (1.0f - e5);
    const float w6 = T6 * (1.0f - e6);
    const float w7 = T7 * (1.0f - e7);

    // Non-temporal stores: weights are write-only here, keep them out of L3
    f32x4 wa = {w0, w1, w2, w3};
    f32x4 wb = {w4, w5, w6, w7};
    __builtin_nontemporal_store(wa, (f32x4*)(out_w + base));
    __builtin_nontemporal_store(wb, (f32x4*)(out_w + base + 4));

    // Per-lane partials
    float cr  = w0 * q0.x + w1 * q0.w + w2 * q1.z + w3 * q2.y
              + w4 * q3.x + w5 * q3.w + w6 * q4.z + w7 * q5.y;
    float cg  = w0 * q0.y + w1 * q1.x + w2 * q1.w + w3 * q2.z
              + w4 * q3.y + w5 * q4.x + w6 * q4.w + w7 * q5.z;
    float cb  = w0 * q0.z + w1 * q1.y + w2 * q2.x + w3 * q2.w
              + w4 * q3.z + w5 * q4.y + w6 * q5.x + w7 * q5.w;
    float dep = w0 * ta.x + w1 * ta.y + w2 * ta.z + w3 * ta.w
              + w4 * tb.x + w5 * tb.y + w6 * tb.z + w7 * tb.w;
    float acc = (w0 + w1 + w2 + w3) + (w4 + w5 + w6 + w7);

    // Butterfly reduce within the 16-lane segment
    #pragma unroll
    for (int off = 8; off; off >>= 1) {
        cr  += __shfl_xor(cr,  off);
        cg  += __shfl_xor(cg,  off);
        cb  += __shfl_xor(cb,  off);
        dep += __shfl_xor(dep, off);
        acc += __shfl_xor(acc, off);
    }

    if (seg == 0) {
        out_rgb[ray * 3 + 0] = cr;
        out_rgb[ray * 3 + 1] = cg;
        out_rgb[ray * 3 + 2] = cb;
        out_depth[ray] = dep;
        out_acc[ray]   = acc;
    }
}
}  // namespace

extern "C" void kernel_launch(void* const* d_in, const int* in_sizes, int n_in,
                              void* d_out, int out_size, void* d_ws, size_t ws_size,
                              hipStream_t stream) {
    const float* dens  = (const float*)d_in[0];  // [B,N,S,1]
    const float* rgbs  = (const float*)d_in[1];  // [B,N,S,3]
    const float* tvals = (const float*)d_in[2];  // [B,N,S]

    float* out       = (float*)d_out;
    float* out_rgb   = out;                              // B*N*3
    float* out_w     = out_rgb + (long)kRays * 3;        // B*N*S
    float* out_depth = out_w + (long)kRays * kS;         // B*N
    float* out_acc   = out_depth + kRays;                // B*N

    const dim3 grid(kRays / (kWavesPerBlock * 4));
    const dim3 block(kWavesPerBlock * 64);
    hipLaunchKernelGGL(volrender_kernel, grid, block, 0, stream,
                       dens, rgbs, tvals, out_rgb, out_w, out_depth, out_acc);
}